// Round 1
// baseline (65.486 us; speedup 1.0000x reference)
//
#include <hip/hip_runtime.h>
#include <math.h>

#define QDEPTH 10
#define WIRES 10
#define NSTATE 1024     // 2^WIRES
#define NTHREADS 256

// ---------------------------------------------------------------------------
// Kernel 1: precompute the 100 Rot gate matrices (batch-independent).
// PennyLane Rot = RZ(omega) RY(theta) RZ(phi):
//   g00 = e^{-i(phi+omega)/2} cos(th/2)      g01 = -e^{+i(phi-omega)/2} sin(th/2)
//   g10 = e^{-i(phi-omega)/2} sin(th/2)      g11 = e^{+i(phi+omega)/2} cos(th/2)
// Stored as 8 floats per gate: g00r,g00i,g01r,g01i,g10r,g10i,g11r,g11i.
// ---------------------------------------------------------------------------
__global__ void gates_kernel(const float* __restrict__ w, float* __restrict__ g) {
    int i = threadIdx.x;
    if (i >= QDEPTH * WIRES) return;
    float phi = tanhf(w[3 * i + 0]);
    float th  = tanhf(w[3 * i + 1]);
    float om  = tanhf(w[3 * i + 2]);
    float c = cosf(0.5f * th), s = sinf(0.5f * th);
    float a = 0.5f * (phi + om), d = 0.5f * (phi - om);
    float ca = cosf(a), sa = sinf(a);
    float cd = cosf(d), sd = sinf(d);
    float* p = g + 8 * i;
    p[0] =  ca * c;  p[1] = -sa * c;   // g00 = e^{-ia} c
    p[2] = -cd * s;  p[3] = -sd * s;   // g01 = -conj(e^{-id}) s = -(cd + i sd) s
    p[4] =  cd * s;  p[5] = -sd * s;   // g10 = e^{-id} s
    p[6] =  ca * c;  p[7] =  sa * c;   // g11 = conj(e^{-ia}) c
}

// ---------------------------------------------------------------------------
// Kernel 2: one block per batch element; state in LDS (re/im split, dbuf).
// ---------------------------------------------------------------------------
__global__ __launch_bounds__(NTHREADS) void sim_kernel(const float* __restrict__ x,
                                                       const float* __restrict__ gates,
                                                       float* __restrict__ out) {
    __shared__ float bufr[2][NSTATE];
    __shared__ float bufi[2][NSTATE];
    __shared__ float wsum[NTHREADS / 64];

    const int b = blockIdx.x;
    const int t = threadIdx.x;
    const float* xb = x + (size_t)b * NSTATE;

    // ---- amplitude embedding: normalize 1024 pixels to unit L2 norm ----
    float v0 = xb[t], v1 = xb[t + 256], v2 = xb[t + 512], v3 = xb[t + 768];
    float ss = v0 * v0 + v1 * v1 + v2 * v2 + v3 * v3;
#pragma unroll
    for (int off = 1; off < 64; off <<= 1) ss += __shfl_xor(ss, off);
    if ((t & 63) == 0) wsum[t >> 6] = ss;
    __syncthreads();
    float inv = 1.0f / sqrtf(wsum[0] + wsum[1] + wsum[2] + wsum[3]);
    bufr[0][t]       = v0 * inv;  bufi[0][t]       = 0.f;
    bufr[0][t + 256] = v1 * inv;  bufi[0][t + 256] = 0.f;
    bufr[0][t + 512] = v2 * inv;  bufi[0][t + 512] = 0.f;
    bufr[0][t + 768] = v3 * inv;  bufi[0][t + 768] = 0.f;
    __syncthreads();

    int cur = 0;
    for (int l = 0; l < QDEPTH; ++l) {
        // ---- 10 single-qubit Rot gates, in place (disjoint pairs) ----
        for (int q = 0; q < WIRES; ++q) {
            const float* gp = gates + 8 * (l * WIRES + q);
            float g00r = gp[0], g00i = gp[1], g01r = gp[2], g01i = gp[3];
            float g10r = gp[4], g10i = gp[5], g11r = gp[6], g11i = gp[7];
            const int bp   = (WIRES - 1) - q;       // flat-index bit for wire q
            const int mask = (1 << bp) - 1;
#pragma unroll
            for (int k = 0; k < 2; ++k) {
                int p  = t + k * NTHREADS;          // pair id 0..511
                int i0 = ((p & ~mask) << 1) | (p & mask);
                int i1 = i0 | (1 << bp);
                float s0r = bufr[cur][i0], s0i = bufi[cur][i0];
                float s1r = bufr[cur][i1], s1i = bufi[cur][i1];
                float n0r = g00r * s0r - g00i * s0i + g01r * s1r - g01i * s1i;
                float n0i = g00r * s0i + g00i * s0r + g01r * s1i + g01i * s1r;
                float n1r = g10r * s0r - g10i * s0i + g11r * s1r - g11i * s1i;
                float n1i = g10r * s0i + g10i * s0r + g11r * s1i + g11i * s1r;
                bufr[cur][i0] = n0r;  bufi[cur][i0] = n0i;
                bufr[cur][i1] = n1r;  bufi[cur][i1] = n1i;
            }
            __syncthreads();
        }

        // ---- CNOT chain = one GF(2)-linear gather: new[idx] = old[G(idx)]
        // G = g_0∘g_1∘…∘g_9 (g_9 applied innermost), g_q: flip tgt bit if ctrl set.
        const int r   = (l % (WIRES - 1)) + 1;
        const int nxt = cur ^ 1;
#pragma unroll
        for (int k = 0; k < 4; ++k) {
            int idx = t + k * NTHREADS;
            unsigned s = (unsigned)idx;
#pragma unroll
            for (int q = WIRES - 1; q >= 0; --q) {
                int cb = (WIRES - 1) - q;
                int tb = (WIRES - 1) - ((q + r) % WIRES);
                s ^= ((s >> cb) & 1u) << tb;
            }
            bufr[nxt][idx] = bufr[cur][s];
            bufi[nxt][idx] = bufi[cur][s];
        }
        cur = nxt;
        __syncthreads();
    }

    // ---- probs = clip(|amp|^2 * 1024, 0, 1) ----
    float* ob = out + (size_t)b * NSTATE;
#pragma unroll
    for (int k = 0; k < 4; ++k) {
        int idx = t + k * NTHREADS;
        float re = bufr[cur][idx], im = bufi[cur][idx];
        float pb = (re * re + im * im) * (float)NSTATE;
        pb = fminf(fmaxf(pb, 0.f), 1.f);
        ob[idx] = pb;
    }
}

extern "C" void kernel_launch(void* const* d_in, const int* in_sizes, int n_in,
                              void* d_out, int out_size, void* d_ws, size_t ws_size,
                              hipStream_t stream) {
    const float* x = (const float*)d_in[0];       // [1024,1,32,32] f32
    const float* w = (const float*)d_in[1];       // [10,10,3] f32
    float* out   = (float*)d_out;                 // [1024,1,32,32] f32
    float* gates = (float*)d_ws;                  // 100*8 floats scratch

    gates_kernel<<<1, 128, 0, stream>>>(w, gates);
    sim_kernel<<<1024, NTHREADS, 0, stream>>>(x, gates, out);
}